// Round 1
// baseline (813.672 us; speedup 1.0000x reference)
//
#include <hip/hip_runtime.h>

#define NN 100000
#define NE 1600000
#define CIN 64
#define HIDN 32
#define NG 128
#define SLOPE 0.01f

// ---------------- setup kernels ----------------

__global__ __launch_bounds__(256) void k_hist(const int* __restrict__ dst,
                                              const int* __restrict__ batch,
                                              int* __restrict__ deg,
                                              int* __restrict__ cnt) {
  int i = blockIdx.x * 256 + threadIdx.x;
  if (i < NE) atomicAdd(&deg[dst[i]], 1);
  if (i < NN) atomicAdd(&cnt[batch[i]], 1);
}

__global__ __launch_bounds__(256) void k_norm(const int* __restrict__ deg,
                                              const int* __restrict__ cnt,
                                              float* __restrict__ dinv,
                                              float* __restrict__ cinv) {
  int i = blockIdx.x * 256 + threadIdx.x;
  if (i < NN) dinv[i] = rsqrtf((float)deg[i] + 1.0f);
  if (i < NG) cinv[i] = 1.0f / (3.0f * fmaxf((float)cnt[i], 1.0f));
}

// ---------------- prefix scan (3-kernel), 1024 items/block ----------------

__global__ __launch_bounds__(256) void k_scan1(const int* __restrict__ deg,
                                               int* __restrict__ bsum) {
  __shared__ int s[256];
  int t = threadIdx.x;
  int base = blockIdx.x * 1024 + t * 4;
  int sum = 0;
#pragma unroll
  for (int j = 0; j < 4; ++j) {
    int idx = base + j;
    if (idx < NN) sum += deg[idx];
  }
  s[t] = sum;
  __syncthreads();
  for (int o = 128; o > 0; o >>= 1) {
    if (t < o) s[t] += s[t + o];
    __syncthreads();
  }
  if (t == 0) bsum[blockIdx.x] = s[0];
}

__global__ __launch_bounds__(128) void k_scan2(int* __restrict__ bsum,
                                               int* __restrict__ rowp, int nblk) {
  __shared__ int s[128];
  int t = threadIdx.x;
  if (t < nblk) s[t] = bsum[t];
  __syncthreads();
  if (t == 0) {
    int run = 0;
    for (int i = 0; i < nblk; ++i) {
      int v = s[i];
      s[i] = run;
      run += v;
    }
    rowp[NN] = run;  // == NE
  }
  __syncthreads();
  if (t < nblk) bsum[t] = s[t];
}

__global__ __launch_bounds__(256) void k_scan3(const int* __restrict__ deg,
                                               const int* __restrict__ bsum,
                                               int* __restrict__ rowp) {
  __shared__ int s[256];
  int t = threadIdx.x;
  int base = blockIdx.x * 1024 + t * 4;
  int d0 = 0, d1 = 0, d2 = 0, d3 = 0;
  if (base < NN) d0 = deg[base];
  if (base + 1 < NN) d1 = deg[base + 1];
  if (base + 2 < NN) d2 = deg[base + 2];
  if (base + 3 < NN) d3 = deg[base + 3];
  int ts = d0 + d1 + d2 + d3;
  s[t] = ts;
  __syncthreads();
  // Hillis-Steele inclusive scan over 256 thread sums
  for (int o = 1; o < 256; o <<= 1) {
    int v = (t >= o) ? s[t - o] : 0;
    __syncthreads();
    s[t] += v;
    __syncthreads();
  }
  int run = bsum[blockIdx.x] + s[t] - ts;  // exclusive prefix for this thread
  if (base < NN) { rowp[base] = run; run += d0; }
  if (base + 1 < NN) { rowp[base + 1] = run; run += d1; }
  if (base + 2 < NN) { rowp[base + 2] = run; run += d2; }
  if (base + 3 < NN) { rowp[base + 3] = run; run += d3; }
}

__global__ __launch_bounds__(256) void k_fill(const int* __restrict__ src,
                                              const int* __restrict__ dst,
                                              const int* __restrict__ rowp,
                                              int* __restrict__ fill,
                                              int* __restrict__ col) {
  int e = blockIdx.x * 256 + threadIdx.x;
  if (e >= NE) return;
  int d = dst[e];
  int p = rowp[d] + atomicAdd(&fill[d], 1);
  col[p] = src[e];
}

// ---------------- dense h = in @ W ----------------
// thread t -> node = gid>>5, feature f = gid&31 (coalesced writes)

template <int K>
__global__ __launch_bounds__(256) void k_mm(const float* __restrict__ in,
                                            const float* __restrict__ W,
                                            float* __restrict__ out) {
  __shared__ float sW[K * HIDN];
  int t = threadIdx.x;
  for (int i = t; i < K * HIDN; i += 256) sW[i] = W[i];
  __syncthreads();
  int gid = blockIdx.x * 256 + t;
  int node = gid >> 5;
  int f = gid & 31;
  if (node >= NN) return;
  const float* xr = in + node * K;
  float acc = 0.f;
#pragma unroll
  for (int k = 0; k < K; ++k) acc += xr[k] * sW[k * HIDN + f];
  out[node * HIDN + f] = acc;
}

// ---------------- CSR aggregation + bias + leakyReLU + fused mean-pool ----------------
// 32 lanes per node (lane = feature). Block handles 32 consecutive nodes (4 iters x 8).

__global__ __launch_bounds__(256) void k_agg(const float* __restrict__ hmm,
                                             const int* __restrict__ rowp,
                                             const int* __restrict__ col,
                                             const float* __restrict__ dinv,
                                             const int* __restrict__ batch,
                                             const float* __restrict__ cinv,
                                             const float* __restrict__ bias,
                                             float* __restrict__ hout,
                                             float* __restrict__ pool) {
  const int t = threadIdx.x;
  const int f = t & 31;
  const int sub = t >> 5;  // 0..7
  const float bf = bias[f];
  float pacc = 0.f;
  int gcur = -1;
  const int base = blockIdx.x * 32;
#pragma unroll
  for (int it = 0; it < 4; ++it) {
    const int i = base + it * 8 + sub;
    if (i < NN) {
      const float di = dinv[i];
      float acc = di * hmm[i * HIDN + f];  // self-loop (dinv_i factored out)
      const int rs = rowp[i];
      const int re = rowp[i + 1];
      int e = rs;
      for (; e + 4 <= re; e += 4) {
        const int c0 = col[e], c1 = col[e + 1], c2 = col[e + 2], c3 = col[e + 3];
        const float w0 = dinv[c0], w1 = dinv[c1], w2 = dinv[c2], w3 = dinv[c3];
        const float v0 = hmm[c0 * HIDN + f], v1 = hmm[c1 * HIDN + f];
        const float v2 = hmm[c2 * HIDN + f], v3 = hmm[c3 * HIDN + f];
        acc += w0 * v0 + w1 * v1 + w2 * v2 + w3 * v3;
      }
      for (; e < re; ++e) {
        const int c = col[e];
        acc += dinv[c] * hmm[c * HIDN + f];
      }
      float v = acc * di + bf;
      v = v > 0.f ? v : SLOPE * v;
      hout[i * HIDN + f] = v;
      const int g = batch[i];
      if (g != gcur) {
        if (gcur >= 0) unsafeAtomicAdd(&pool[gcur * HIDN + f], pacc * cinv[gcur]);
        gcur = g;
        pacc = 0.f;
      }
      pacc += v;
    }
  }
  if (gcur >= 0) unsafeAtomicAdd(&pool[gcur * HIDN + f], pacc * cinv[gcur]);
}

// ---------------- launch ----------------

extern "C" void kernel_launch(void* const* d_in, const int* in_sizes, int n_in,
                              void* d_out, int out_size, void* d_ws, size_t ws_size,
                              hipStream_t stream) {
  const float* x = (const float*)d_in[0];
  const float* W0 = (const float*)d_in[1];
  const float* b0 = (const float*)d_in[2];
  const float* W1 = (const float*)d_in[3];
  const float* b1 = (const float*)d_in[4];
  const float* W2 = (const float*)d_in[5];
  const float* b2 = (const float*)d_in[6];
  const int* src = (const int*)d_in[7];
  const int* dst = (const int*)d_in[8];
  const int* batch = (const int*)d_in[9];
  float* out = (float*)d_out;

  char* ws = (char*)d_ws;
  auto carve = [&](size_t bytes) -> char* {
    char* p = ws;
    ws += (bytes + 255) & ~(size_t)255;
    return p;
  };
  int* deg = (int*)carve(NN * 4);
  int* fill = (int*)carve(NN * 4);
  int* cnt = (int*)carve(NG * 4);
  int* rowp = (int*)carve((NN + 1) * 4);
  int* bsum = (int*)carve(128 * 4);
  float* dinv = (float*)carve(NN * 4);
  float* cinv = (float*)carve(NG * 4);
  int* col = (int*)carve(NE * 4);
  float* hA = (float*)carve((size_t)NN * HIDN * 4);
  float* hB = (float*)carve((size_t)NN * HIDN * 4);

  hipMemsetAsync(deg, 0, NN * 4, stream);
  hipMemsetAsync(fill, 0, NN * 4, stream);
  hipMemsetAsync(cnt, 0, NG * 4, stream);
  hipMemsetAsync(out, 0, NG * HIDN * 4, stream);

  k_hist<<<(NE + 255) / 256, 256, 0, stream>>>(dst, batch, deg, cnt);
  k_norm<<<(NN + 255) / 256, 256, 0, stream>>>(deg, cnt, dinv, cinv);

  int nblk = (NN + 1023) / 1024;  // 98
  k_scan1<<<nblk, 256, 0, stream>>>(deg, bsum);
  k_scan2<<<1, 128, 0, stream>>>(bsum, rowp, nblk);
  k_scan3<<<nblk, 256, 0, stream>>>(deg, bsum, rowp);
  k_fill<<<(NE + 255) / 256, 256, 0, stream>>>(src, dst, rowp, fill, col);

  const int mm_grid = (NN * HIDN + 255) / 256;  // 12500
  const int agg_grid = (NN + 31) / 32;          // 3125

  // layer 0
  k_mm<CIN><<<mm_grid, 256, 0, stream>>>(x, W0, hB);
  k_agg<<<agg_grid, 256, 0, stream>>>(hB, rowp, col, dinv, batch, cinv, b0, hA, out);
  // layer 1
  k_mm<HIDN><<<mm_grid, 256, 0, stream>>>(hA, W1, hB);
  k_agg<<<agg_grid, 256, 0, stream>>>(hB, rowp, col, dinv, batch, cinv, b1, hA, out);
  // layer 2
  k_mm<HIDN><<<mm_grid, 256, 0, stream>>>(hA, W2, hB);
  k_agg<<<agg_grid, 256, 0, stream>>>(hB, rowp, col, dinv, batch, cinv, b2, hA, out);
}

// Round 2
// 575.105 us; speedup vs baseline: 1.4148x; 1.4148x over previous
//
#include <hip/hip_runtime.h>

#define NN 100000
#define NE 1600000
#define CIN 64
#define HIDN 32
#define NG 128
#define SLOPE 0.01f

// ---------------- degree histogram (deg only; batch counts via binary search) ----------------

__global__ __launch_bounds__(256) void k_deg(const int* __restrict__ dst,
                                             int* __restrict__ deg) {
  int i = blockIdx.x * 256 + threadIdx.x;
  if (i < NE) atomicAdd(&deg[dst[i]], 1);
}

// batch is sorted: counts per group = boundary differences via binary search.
__global__ __launch_bounds__(256) void k_cnt(const int* __restrict__ batch,
                                             float* __restrict__ cinv) {
  __shared__ int sb[NG + 1];
  int g = threadIdx.x;
  if (g <= NG) {
    int lo = 0, hi = NN;  // lower_bound of g
    while (lo < hi) {
      int mid = (lo + hi) >> 1;
      if (batch[mid] < g) lo = mid + 1; else hi = mid;
    }
    sb[g] = lo;
  }
  __syncthreads();
  if (g < NG) {
    int c = sb[g + 1] - sb[g];
    cinv[g] = 1.0f / (3.0f * fmaxf((float)c, 1.0f));
  }
}

__global__ __launch_bounds__(256) void k_norm(const int* __restrict__ deg,
                                              float* __restrict__ dinv) {
  int i = blockIdx.x * 256 + threadIdx.x;
  if (i < NN) dinv[i] = rsqrtf((float)deg[i] + 1.0f);
}

// ---------------- prefix scan (3-kernel), 1024 items/block ----------------

__global__ __launch_bounds__(256) void k_scan1(const int* __restrict__ deg,
                                               int* __restrict__ bsum) {
  __shared__ int s[256];
  int t = threadIdx.x;
  int base = blockIdx.x * 1024 + t * 4;
  int sum = 0;
#pragma unroll
  for (int j = 0; j < 4; ++j) {
    int idx = base + j;
    if (idx < NN) sum += deg[idx];
  }
  s[t] = sum;
  __syncthreads();
  for (int o = 128; o > 0; o >>= 1) {
    if (t < o) s[t] += s[t + o];
    __syncthreads();
  }
  if (t == 0) bsum[blockIdx.x] = s[0];
}

__global__ __launch_bounds__(128) void k_scan2(int* __restrict__ bsum,
                                               int* __restrict__ rowp, int nblk) {
  __shared__ int s[128];
  int t = threadIdx.x;
  if (t < nblk) s[t] = bsum[t];
  __syncthreads();
  if (t == 0) {
    int run = 0;
    for (int i = 0; i < nblk; ++i) {
      int v = s[i];
      s[i] = run;
      run += v;
    }
    rowp[NN] = run;  // == NE
  }
  __syncthreads();
  if (t < nblk) bsum[t] = s[t];
}

__global__ __launch_bounds__(256) void k_scan3(const int* __restrict__ deg,
                                               const int* __restrict__ bsum,
                                               int* __restrict__ rowp) {
  __shared__ int s[256];
  int t = threadIdx.x;
  int base = blockIdx.x * 1024 + t * 4;
  int d0 = 0, d1 = 0, d2 = 0, d3 = 0;
  if (base < NN) d0 = deg[base];
  if (base + 1 < NN) d1 = deg[base + 1];
  if (base + 2 < NN) d2 = deg[base + 2];
  if (base + 3 < NN) d3 = deg[base + 3];
  int ts = d0 + d1 + d2 + d3;
  s[t] = ts;
  __syncthreads();
  for (int o = 1; o < 256; o <<= 1) {
    int v = (t >= o) ? s[t - o] : 0;
    __syncthreads();
    s[t] += v;
    __syncthreads();
  }
  int run = bsum[blockIdx.x] + s[t] - ts;  // exclusive prefix for this thread
  if (base < NN) { rowp[base] = run; run += d0; }
  if (base + 1 < NN) { rowp[base + 1] = run; run += d1; }
  if (base + 2 < NN) { rowp[base + 2] = run; run += d2; }
  if (base + 3 < NN) { rowp[base + 3] = run; run += d3; }
}

// cur[] starts as a copy of rowp[]; atomic bump gives final position directly.
__global__ __launch_bounds__(256) void k_fill(const int* __restrict__ src,
                                              const int* __restrict__ dst,
                                              int* __restrict__ cur,
                                              int* __restrict__ col) {
  int e = blockIdx.x * 256 + threadIdx.x;
  if (e >= NE) return;
  int p = atomicAdd(&cur[dst[e]], 1);
  col[p] = src[e];
}

// ---------------- dense h = in @ W ----------------

template <int K>
__global__ __launch_bounds__(256) void k_mm(const float* __restrict__ in,
                                            const float* __restrict__ W,
                                            float* __restrict__ out) {
  __shared__ float sW[K * HIDN];
  int t = threadIdx.x;
  for (int i = t; i < K * HIDN; i += 256) sW[i] = W[i];
  __syncthreads();
  int gid = blockIdx.x * 256 + t;
  int node = gid >> 5;
  int f = gid & 31;
  if (node >= NN) return;
  const float* xr = in + node * K;
  float acc = 0.f;
#pragma unroll
  for (int k = 0; k < K; ++k) acc += xr[k] * sW[k * HIDN + f];
  out[node * HIDN + f] = acc;
}

// ---------------- CSR aggregation + bias + leakyReLU + fused mean-pool ----------------

__global__ __launch_bounds__(256) void k_agg(const float* __restrict__ hmm,
                                             const int* __restrict__ rowp,
                                             const int* __restrict__ col,
                                             const float* __restrict__ dinv,
                                             const int* __restrict__ batch,
                                             const float* __restrict__ cinv,
                                             const float* __restrict__ bias,
                                             float* __restrict__ hout,
                                             float* __restrict__ pool) {
  const int t = threadIdx.x;
  const int f = t & 31;
  const int sub = t >> 5;  // 0..7
  const float bf = bias[f];
  float pacc = 0.f;
  int gcur = -1;
  const int base = blockIdx.x * 32;
#pragma unroll
  for (int it = 0; it < 4; ++it) {
    const int i = base + it * 8 + sub;
    if (i < NN) {
      const float di = dinv[i];
      float acc = di * hmm[i * HIDN + f];  // self-loop (dinv_i factored out)
      const int rs = rowp[i];
      const int re = rowp[i + 1];
      int e = rs;
      for (; e + 4 <= re; e += 4) {
        const int c0 = col[e], c1 = col[e + 1], c2 = col[e + 2], c3 = col[e + 3];
        const float w0 = dinv[c0], w1 = dinv[c1], w2 = dinv[c2], w3 = dinv[c3];
        const float v0 = hmm[c0 * HIDN + f], v1 = hmm[c1 * HIDN + f];
        const float v2 = hmm[c2 * HIDN + f], v3 = hmm[c3 * HIDN + f];
        acc += w0 * v0 + w1 * v1 + w2 * v2 + w3 * v3;
      }
      for (; e < re; ++e) {
        const int c = col[e];
        acc += dinv[c] * hmm[c * HIDN + f];
      }
      float v = acc * di + bf;
      v = v > 0.f ? v : SLOPE * v;
      hout[i * HIDN + f] = v;
      const int g = batch[i];
      if (g != gcur) {
        if (gcur >= 0) unsafeAtomicAdd(&pool[gcur * HIDN + f], pacc * cinv[gcur]);
        gcur = g;
        pacc = 0.f;
      }
      pacc += v;
    }
  }
  if (gcur >= 0) unsafeAtomicAdd(&pool[gcur * HIDN + f], pacc * cinv[gcur]);
}

// ---------------- launch ----------------

extern "C" void kernel_launch(void* const* d_in, const int* in_sizes, int n_in,
                              void* d_out, int out_size, void* d_ws, size_t ws_size,
                              hipStream_t stream) {
  const float* x = (const float*)d_in[0];
  const float* W0 = (const float*)d_in[1];
  const float* b0 = (const float*)d_in[2];
  const float* W1 = (const float*)d_in[3];
  const float* b1 = (const float*)d_in[4];
  const float* W2 = (const float*)d_in[5];
  const float* b2 = (const float*)d_in[6];
  const int* src = (const int*)d_in[7];
  const int* dst = (const int*)d_in[8];
  const int* batch = (const int*)d_in[9];
  float* out = (float*)d_out;

  char* ws = (char*)d_ws;
  auto carve = [&](size_t bytes) -> char* {
    char* p = ws;
    ws += (bytes + 255) & ~(size_t)255;
    return p;
  };
  int* deg = (int*)carve(NN * 4);
  int* cur = (int*)carve(NN * 4);
  int* rowp = (int*)carve((NN + 1) * 4);
  int* bsum = (int*)carve(128 * 4);
  float* dinv = (float*)carve(NN * 4);
  float* cinv = (float*)carve(NG * 4);
  int* col = (int*)carve(NE * 4);
  float* hA = (float*)carve((size_t)NN * HIDN * 4);
  float* hB = (float*)carve((size_t)NN * HIDN * 4);

  hipMemsetAsync(deg, 0, NN * 4, stream);
  hipMemsetAsync(out, 0, NG * HIDN * 4, stream);

  k_deg<<<(NE + 255) / 256, 256, 0, stream>>>(dst, deg);
  k_cnt<<<1, 256, 0, stream>>>(batch, cinv);
  k_norm<<<(NN + 255) / 256, 256, 0, stream>>>(deg, dinv);

  int nblk = (NN + 1023) / 1024;  // 98
  k_scan1<<<nblk, 256, 0, stream>>>(deg, bsum);
  k_scan2<<<1, 128, 0, stream>>>(bsum, rowp, nblk);
  k_scan3<<<nblk, 256, 0, stream>>>(deg, bsum, rowp);
  hipMemcpyAsync(cur, rowp, NN * 4, hipMemcpyDeviceToDevice, stream);
  k_fill<<<(NE + 255) / 256, 256, 0, stream>>>(src, dst, cur, col);

  const int mm_grid = (NN * HIDN + 255) / 256;  // 12500
  const int agg_grid = (NN + 31) / 32;          // 3125

  // layer 0
  k_mm<CIN><<<mm_grid, 256, 0, stream>>>(x, W0, hB);
  k_agg<<<agg_grid, 256, 0, stream>>>(hB, rowp, col, dinv, batch, cinv, b0, hA, out);
  // layer 1
  k_mm<HIDN><<<mm_grid, 256, 0, stream>>>(hA, W1, hB);
  k_agg<<<agg_grid, 256, 0, stream>>>(hB, rowp, col, dinv, batch, cinv, b1, hA, out);
  // layer 2
  k_mm<HIDN><<<mm_grid, 256, 0, stream>>>(hA, W2, hB);
  k_agg<<<agg_grid, 256, 0, stream>>>(hB, rowp, col, dinv, batch, cinv, b2, hA, out);
}

// Round 3
// 473.540 us; speedup vs baseline: 1.7183x; 1.2145x over previous
//
#include <hip/hip_runtime.h>

#define NN 100000
#define NE 1600000
#define CIN 64
#define HIDN 32
#define NG 128
#define SLOPE 0.01f

// batch is sorted: counts per group = boundary differences via binary search.
__global__ __launch_bounds__(256) void k_cnt(const int* __restrict__ batch,
                                             float* __restrict__ cinv) {
  __shared__ int sb[NG + 1];
  int g = threadIdx.x;
  if (g <= NG) {
    int lo = 0, hi = NN;  // lower_bound of g
    while (lo < hi) {
      int mid = (lo + hi) >> 1;
      if (batch[mid] < g) lo = mid + 1; else hi = mid;
    }
    sb[g] = lo;
  }
  __syncthreads();
  if (g < NG) {
    int c = sb[g + 1] - sb[g];
    cinv[g] = 1.0f / (3.0f * fmaxf((float)c, 1.0f));
  }
}

// ---------------- CSR build: one atomic pass producing ranks ----------------

__global__ __launch_bounds__(256) void k_rank(const int* __restrict__ dst,
                                              int* __restrict__ deg,
                                              int* __restrict__ rank) {
  int i = blockIdx.x * 256 + threadIdx.x;  // quad-edge index
  if (i * 4 >= NE) return;
  int4 d = ((const int4*)dst)[i];
  int4 r;
  r.x = atomicAdd(&deg[d.x], 1);
  r.y = atomicAdd(&deg[d.y], 1);
  r.z = atomicAdd(&deg[d.z], 1);
  r.w = atomicAdd(&deg[d.w], 1);
  ((int4*)rank)[i] = r;
}

__global__ __launch_bounds__(256) void k_norm(const int* __restrict__ deg,
                                              float* __restrict__ dinv) {
  int i = blockIdx.x * 256 + threadIdx.x;
  if (i < NN) dinv[i] = rsqrtf((float)deg[i] + 1.0f);
}

// ---------------- prefix scan (3-kernel), 1024 items/block ----------------

__global__ __launch_bounds__(256) void k_scan1(const int* __restrict__ deg,
                                               int* __restrict__ bsum) {
  __shared__ int s[256];
  int t = threadIdx.x;
  int base = blockIdx.x * 1024 + t * 4;
  int sum = 0;
#pragma unroll
  for (int j = 0; j < 4; ++j) {
    int idx = base + j;
    if (idx < NN) sum += deg[idx];
  }
  s[t] = sum;
  __syncthreads();
  for (int o = 128; o > 0; o >>= 1) {
    if (t < o) s[t] += s[t + o];
    __syncthreads();
  }
  if (t == 0) bsum[blockIdx.x] = s[0];
}

__global__ __launch_bounds__(128) void k_scan2(int* __restrict__ bsum,
                                               int* __restrict__ rowp, int nblk) {
  __shared__ int s[128];
  int t = threadIdx.x;
  if (t < nblk) s[t] = bsum[t];
  __syncthreads();
  if (t == 0) {
    int run = 0;
    for (int i = 0; i < nblk; ++i) {
      int v = s[i];
      s[i] = run;
      run += v;
    }
    rowp[NN] = run;  // == NE
  }
  __syncthreads();
  if (t < nblk) bsum[t] = s[t];
}

__global__ __launch_bounds__(256) void k_scan3(const int* __restrict__ deg,
                                               const int* __restrict__ bsum,
                                               int* __restrict__ rowp) {
  __shared__ int s[256];
  int t = threadIdx.x;
  int base = blockIdx.x * 1024 + t * 4;
  int d0 = 0, d1 = 0, d2 = 0, d3 = 0;
  if (base < NN) d0 = deg[base];
  if (base + 1 < NN) d1 = deg[base + 1];
  if (base + 2 < NN) d2 = deg[base + 2];
  if (base + 3 < NN) d3 = deg[base + 3];
  int ts = d0 + d1 + d2 + d3;
  s[t] = ts;
  __syncthreads();
  for (int o = 1; o < 256; o <<= 1) {
    int v = (t >= o) ? s[t - o] : 0;
    __syncthreads();
    s[t] += v;
    __syncthreads();
  }
  int run = bsum[blockIdx.x] + s[t] - ts;  // exclusive prefix for this thread
  if (base < NN) { rowp[base] = run; run += d0; }
  if (base + 1 < NN) { rowp[base + 1] = run; run += d1; }
  if (base + 2 < NN) { rowp[base + 2] = run; run += d2; }
  if (base + 3 < NN) { rowp[base + 3] = run; run += d3; }
}

// no atomics: position = rowp[dst] + precomputed rank
__global__ __launch_bounds__(256) void k_scatter(const int* __restrict__ src,
                                                 const int* __restrict__ dst,
                                                 const int* __restrict__ rank,
                                                 const int* __restrict__ rowp,
                                                 int* __restrict__ col) {
  int i = blockIdx.x * 256 + threadIdx.x;  // quad-edge index
  if (i * 4 >= NE) return;
  int4 d = ((const int4*)dst)[i];
  int4 r = ((const int4*)rank)[i];
  int4 s = ((const int4*)src)[i];
  col[rowp[d.x] + r.x] = s.x;
  col[rowp[d.y] + r.y] = s.y;
  col[rowp[d.z] + r.z] = s.z;
  col[rowp[d.w] + r.w] = s.w;
}

// ---------------- dense hs = dinv ⊙ (in @ W) ----------------

template <int K>
__global__ __launch_bounds__(256) void k_mm(const float* __restrict__ in,
                                            const float* __restrict__ W,
                                            const float* __restrict__ dinv,
                                            float* __restrict__ out) {
  __shared__ float sW[K * HIDN];
  int t = threadIdx.x;
  for (int i = t; i < K * HIDN; i += 256) sW[i] = W[i];
  __syncthreads();
  int gid = blockIdx.x * 256 + t;
  int node = gid >> 5;
  int f = gid & 31;
  if (node >= NN) return;
  const float* xr = in + node * K;
  float acc = 0.f;
#pragma unroll
  for (int k = 0; k < K; ++k) acc += xr[k] * sW[k * HIDN + f];
  out[node * HIDN + f] = acc * dinv[node];
}

// ---------------- CSR aggregation + bias + leakyReLU + fused mean-pool ----------------
// hs rows are pre-scaled by dinv: agg_i = dinv_i * (hs_i + sum_c hs_c)

__global__ __launch_bounds__(256) void k_agg(const float* __restrict__ hs,
                                             const int* __restrict__ rowp,
                                             const int* __restrict__ col,
                                             const float* __restrict__ dinv,
                                             const int* __restrict__ batch,
                                             const float* __restrict__ cinv,
                                             const float* __restrict__ bias,
                                             float* __restrict__ hout,
                                             float* __restrict__ pool) {
  const int t = threadIdx.x;
  const int f = t & 31;
  const int sub = t >> 5;  // 0..7
  const float bf = bias[f];
  float pacc = 0.f;
  int gcur = -1;
  const int base = blockIdx.x * 32;
#pragma unroll
  for (int it = 0; it < 4; ++it) {
    const int i = base + it * 8 + sub;
    if (i < NN) {
      float acc = hs[i * HIDN + f];  // self-loop term (pre-scaled)
      const int rs = rowp[i];
      const int re = rowp[i + 1];
      int e = rs;
      for (; e + 4 <= re; e += 4) {
        const int c0 = col[e], c1 = col[e + 1], c2 = col[e + 2], c3 = col[e + 3];
        const float v0 = hs[c0 * HIDN + f], v1 = hs[c1 * HIDN + f];
        const float v2 = hs[c2 * HIDN + f], v3 = hs[c3 * HIDN + f];
        acc += (v0 + v1) + (v2 + v3);
      }
      for (; e < re; ++e) acc += hs[col[e] * HIDN + f];
      float v = acc * dinv[i] + bf;
      v = v > 0.f ? v : SLOPE * v;
      hout[i * HIDN + f] = v;
      const int g = batch[i];
      if (g != gcur) {
        if (gcur >= 0) unsafeAtomicAdd(&pool[gcur * HIDN + f], pacc * cinv[gcur]);
        gcur = g;
        pacc = 0.f;
      }
      pacc += v;
    }
  }
  if (gcur >= 0) unsafeAtomicAdd(&pool[gcur * HIDN + f], pacc * cinv[gcur]);
}

// ---------------- launch ----------------

extern "C" void kernel_launch(void* const* d_in, const int* in_sizes, int n_in,
                              void* d_out, int out_size, void* d_ws, size_t ws_size,
                              hipStream_t stream) {
  const float* x = (const float*)d_in[0];
  const float* W0 = (const float*)d_in[1];
  const float* b0 = (const float*)d_in[2];
  const float* W1 = (const float*)d_in[3];
  const float* b1 = (const float*)d_in[4];
  const float* W2 = (const float*)d_in[5];
  const float* b2 = (const float*)d_in[6];
  const int* src = (const int*)d_in[7];
  const int* dst = (const int*)d_in[8];
  const int* batch = (const int*)d_in[9];
  float* out = (float*)d_out;

  char* ws = (char*)d_ws;
  auto carve = [&](size_t bytes) -> char* {
    char* p = ws;
    ws += (bytes + 255) & ~(size_t)255;
    return p;
  };
  int* deg = (int*)carve(NN * 4);
  int* rank = (int*)carve((size_t)NE * 4);
  int* rowp = (int*)carve((NN + 1) * 4);
  int* bsum = (int*)carve(128 * 4);
  float* dinv = (float*)carve(NN * 4);
  float* cinv = (float*)carve(NG * 4);
  int* col = (int*)carve((size_t)NE * 4);
  float* hA = (float*)carve((size_t)NN * HIDN * 4);
  float* hs = (float*)carve((size_t)NN * HIDN * 4);

  hipMemsetAsync(deg, 0, NN * 4, stream);
  hipMemsetAsync(out, 0, NG * HIDN * 4, stream);

  k_cnt<<<1, 256, 0, stream>>>(batch, cinv);

  const int quad_grid = (NE / 4 + 255) / 256;  // 1563
  k_rank<<<quad_grid, 256, 0, stream>>>(dst, deg, rank);
  k_norm<<<(NN + 255) / 256, 256, 0, stream>>>(deg, dinv);

  int nblk = (NN + 1023) / 1024;  // 98
  k_scan1<<<nblk, 256, 0, stream>>>(deg, bsum);
  k_scan2<<<1, 128, 0, stream>>>(bsum, rowp, nblk);
  k_scan3<<<nblk, 256, 0, stream>>>(deg, bsum, rowp);
  k_scatter<<<quad_grid, 256, 0, stream>>>(src, dst, rank, rowp, col);

  const int mm_grid = (NN * HIDN + 255) / 256;  // 12500
  const int agg_grid = (NN + 31) / 32;          // 3125

  // layer 0
  k_mm<CIN><<<mm_grid, 256, 0, stream>>>(x, W0, dinv, hs);
  k_agg<<<agg_grid, 256, 0, stream>>>(hs, rowp, col, dinv, batch, cinv, b0, hA, out);
  // layer 1
  k_mm<HIDN><<<mm_grid, 256, 0, stream>>>(hA, W1, dinv, hs);
  k_agg<<<agg_grid, 256, 0, stream>>>(hs, rowp, col, dinv, batch, cinv, b1, hA, out);
  // layer 2
  k_mm<HIDN><<<mm_grid, 256, 0, stream>>>(hA, W2, dinv, hs);
  k_agg<<<agg_grid, 256, 0, stream>>>(hs, rowp, col, dinv, batch, cinv, b2, hA, out);
}

// Round 4
// 468.008 us; speedup vs baseline: 1.7386x; 1.0118x over previous
//
#include <hip/hip_runtime.h>
#include <hip/hip_bf16.h>

#define NN 100000
#define NE 1600000
#define CIN 64
#define HIDN 32
#define NG 128
#define SLOPE 0.01f

// batch is sorted: counts per group = boundary differences via binary search.
__global__ __launch_bounds__(256) void k_cnt(const int* __restrict__ batch,
                                             float* __restrict__ cinv) {
  __shared__ int sb[NG + 1];
  int g = threadIdx.x;
  if (g <= NG) {
    int lo = 0, hi = NN;  // lower_bound of g
    while (lo < hi) {
      int mid = (lo + hi) >> 1;
      if (batch[mid] < g) lo = mid + 1; else hi = mid;
    }
    sb[g] = lo;
  }
  __syncthreads();
  if (g < NG) {
    int c = sb[g + 1] - sb[g];
    cinv[g] = 1.0f / (3.0f * fmaxf((float)c, 1.0f));
  }
}

// ---------------- CSR build: one atomic pass producing ranks ----------------

__global__ __launch_bounds__(256) void k_rank(const int* __restrict__ dst,
                                              int* __restrict__ deg,
                                              int* __restrict__ rank) {
  int i = blockIdx.x * 256 + threadIdx.x;  // quad-edge index
  if (i * 4 >= NE) return;
  int4 d = ((const int4*)dst)[i];
  int4 r;
  r.x = atomicAdd(&deg[d.x], 1);
  r.y = atomicAdd(&deg[d.y], 1);
  r.z = atomicAdd(&deg[d.z], 1);
  r.w = atomicAdd(&deg[d.w], 1);
  ((int4*)rank)[i] = r;
}

__global__ __launch_bounds__(256) void k_norm(const int* __restrict__ deg,
                                              float* __restrict__ dinv) {
  int i = blockIdx.x * 256 + threadIdx.x;
  if (i < NN) dinv[i] = rsqrtf((float)deg[i] + 1.0f);
}

// ---------------- prefix scan (3-kernel), 1024 items/block ----------------

__global__ __launch_bounds__(256) void k_scan1(const int* __restrict__ deg,
                                               int* __restrict__ bsum) {
  __shared__ int s[256];
  int t = threadIdx.x;
  int base = blockIdx.x * 1024 + t * 4;
  int sum = 0;
#pragma unroll
  for (int j = 0; j < 4; ++j) {
    int idx = base + j;
    if (idx < NN) sum += deg[idx];
  }
  s[t] = sum;
  __syncthreads();
  for (int o = 128; o > 0; o >>= 1) {
    if (t < o) s[t] += s[t + o];
    __syncthreads();
  }
  if (t == 0) bsum[blockIdx.x] = s[0];
}

__global__ __launch_bounds__(128) void k_scan2(int* __restrict__ bsum,
                                               int* __restrict__ rowp, int nblk) {
  __shared__ int s[128];
  int t = threadIdx.x;
  if (t < nblk) s[t] = bsum[t];
  __syncthreads();
  if (t == 0) {
    int run = 0;
    for (int i = 0; i < nblk; ++i) {
      int v = s[i];
      s[i] = run;
      run += v;
    }
    rowp[NN] = run;  // == NE
  }
  __syncthreads();
  if (t < nblk) bsum[t] = s[t];
}

__global__ __launch_bounds__(256) void k_scan3(const int* __restrict__ deg,
                                               const int* __restrict__ bsum,
                                               int* __restrict__ rowp) {
  __shared__ int s[256];
  int t = threadIdx.x;
  int base = blockIdx.x * 1024 + t * 4;
  int d0 = 0, d1 = 0, d2 = 0, d3 = 0;
  if (base < NN) d0 = deg[base];
  if (base + 1 < NN) d1 = deg[base + 1];
  if (base + 2 < NN) d2 = deg[base + 2];
  if (base + 3 < NN) d3 = deg[base + 3];
  int ts = d0 + d1 + d2 + d3;
  s[t] = ts;
  __syncthreads();
  for (int o = 1; o < 256; o <<= 1) {
    int v = (t >= o) ? s[t - o] : 0;
    __syncthreads();
    s[t] += v;
    __syncthreads();
  }
  int run = bsum[blockIdx.x] + s[t] - ts;  // exclusive prefix for this thread
  if (base < NN) { rowp[base] = run; run += d0; }
  if (base + 1 < NN) { rowp[base + 1] = run; run += d1; }
  if (base + 2 < NN) { rowp[base + 2] = run; run += d2; }
  if (base + 3 < NN) { rowp[base + 3] = run; run += d3; }
}

// no atomics: position = rowp[dst] + precomputed rank
__global__ __launch_bounds__(256) void k_scatter(const int* __restrict__ src,
                                                 const int* __restrict__ dst,
                                                 const int* __restrict__ rank,
                                                 const int* __restrict__ rowp,
                                                 int* __restrict__ col) {
  int i = blockIdx.x * 256 + threadIdx.x;  // quad-edge index
  if (i * 4 >= NE) return;
  int4 d = ((const int4*)dst)[i];
  int4 r = ((const int4*)rank)[i];
  int4 s = ((const int4*)src)[i];
  col[rowp[d.x] + r.x] = s.x;
  col[rowp[d.y] + r.y] = s.y;
  col[rowp[d.z] + r.z] = s.z;
  col[rowp[d.w] + r.w] = s.w;
}

// ---------------- dense hs = bf16( dinv ⊙ (in @ W) ) ----------------

template <int K>
__global__ __launch_bounds__(256) void k_mm(const float* __restrict__ in,
                                            const float* __restrict__ W,
                                            const float* __restrict__ dinv,
                                            __hip_bfloat16* __restrict__ out) {
  __shared__ float sW[K * HIDN];
  int t = threadIdx.x;
  for (int i = t; i < K * HIDN; i += 256) sW[i] = W[i];
  __syncthreads();
  int gid = blockIdx.x * 256 + t;
  int node = gid >> 5;
  int f = gid & 31;
  if (node >= NN) return;
  const float* xr = in + node * K;
  float acc = 0.f;
#pragma unroll
  for (int k = 0; k < K; ++k) acc += xr[k] * sW[k * HIDN + f];
  out[node * HIDN + f] = __float2bfloat16(acc * dinv[node]);
}

// ---------------- CSR aggregation + bias + leakyReLU + fused mean-pool ----------------
// hs rows are bf16, pre-scaled by dinv: agg_i = dinv_i * (hs_i + sum_c hs_c)

template <int WRITE_H>
__global__ __launch_bounds__(256) void k_agg(const __hip_bfloat16* __restrict__ hs,
                                             const int* __restrict__ rowp,
                                             const int* __restrict__ col,
                                             const float* __restrict__ dinv,
                                             const int* __restrict__ batch,
                                             const float* __restrict__ cinv,
                                             const float* __restrict__ bias,
                                             float* __restrict__ hout,
                                             float* __restrict__ pool) {
  const int t = threadIdx.x;
  const int f = t & 31;
  const int sub = t >> 5;  // 0..7
  const float bf = bias[f];
  float pacc = 0.f;
  int gcur = -1;
  const int base = blockIdx.x * 32;
#pragma unroll
  for (int it = 0; it < 4; ++it) {
    const int i = base + it * 8 + sub;
    if (i < NN) {
      float acc = __bfloat162float(hs[i * HIDN + f]);  // self-loop term
      const int rs = rowp[i];
      const int re = rowp[i + 1];
      int e = rs;
      for (; e + 4 <= re; e += 4) {
        const int c0 = col[e], c1 = col[e + 1], c2 = col[e + 2], c3 = col[e + 3];
        const float v0 = __bfloat162float(hs[c0 * HIDN + f]);
        const float v1 = __bfloat162float(hs[c1 * HIDN + f]);
        const float v2 = __bfloat162float(hs[c2 * HIDN + f]);
        const float v3 = __bfloat162float(hs[c3 * HIDN + f]);
        acc += (v0 + v1) + (v2 + v3);
      }
      for (; e < re; ++e) acc += __bfloat162float(hs[col[e] * HIDN + f]);
      float v = acc * dinv[i] + bf;
      v = v > 0.f ? v : SLOPE * v;
      if (WRITE_H) hout[i * HIDN + f] = v;
      const int g = batch[i];
      if (g != gcur) {
        if (gcur >= 0) unsafeAtomicAdd(&pool[gcur * HIDN + f], pacc * cinv[gcur]);
        gcur = g;
        pacc = 0.f;
      }
      pacc += v;
    }
  }
  if (gcur >= 0) unsafeAtomicAdd(&pool[gcur * HIDN + f], pacc * cinv[gcur]);
}

// ---------------- launch ----------------

extern "C" void kernel_launch(void* const* d_in, const int* in_sizes, int n_in,
                              void* d_out, int out_size, void* d_ws, size_t ws_size,
                              hipStream_t stream) {
  const float* x = (const float*)d_in[0];
  const float* W0 = (const float*)d_in[1];
  const float* b0 = (const float*)d_in[2];
  const float* W1 = (const float*)d_in[3];
  const float* b1 = (const float*)d_in[4];
  const float* W2 = (const float*)d_in[5];
  const float* b2 = (const float*)d_in[6];
  const int* src = (const int*)d_in[7];
  const int* dst = (const int*)d_in[8];
  const int* batch = (const int*)d_in[9];
  float* out = (float*)d_out;

  char* ws = (char*)d_ws;
  auto carve = [&](size_t bytes) -> char* {
    char* p = ws;
    ws += (bytes + 255) & ~(size_t)255;
    return p;
  };
  int* deg = (int*)carve(NN * 4);
  int* rank = (int*)carve((size_t)NE * 4);
  int* rowp = (int*)carve((NN + 1) * 4);
  int* bsum = (int*)carve(128 * 4);
  float* dinv = (float*)carve(NN * 4);
  float* cinv = (float*)carve(NG * 4);
  int* col = (int*)carve((size_t)NE * 4);
  float* hA = (float*)carve((size_t)NN * HIDN * 4);
  __hip_bfloat16* hs = (__hip_bfloat16*)carve((size_t)NN * HIDN * 2);

  hipMemsetAsync(deg, 0, NN * 4, stream);
  hipMemsetAsync(out, 0, NG * HIDN * 4, stream);

  k_cnt<<<1, 256, 0, stream>>>(batch, cinv);

  const int quad_grid = (NE / 4 + 255) / 256;  // 1563
  k_rank<<<quad_grid, 256, 0, stream>>>(dst, deg, rank);
  k_norm<<<(NN + 255) / 256, 256, 0, stream>>>(deg, dinv);

  int nblk = (NN + 1023) / 1024;  // 98
  k_scan1<<<nblk, 256, 0, stream>>>(deg, bsum);
  k_scan2<<<1, 128, 0, stream>>>(bsum, rowp, nblk);
  k_scan3<<<nblk, 256, 0, stream>>>(deg, bsum, rowp);
  k_scatter<<<quad_grid, 256, 0, stream>>>(src, dst, rank, rowp, col);

  const int mm_grid = (NN * HIDN + 255) / 256;  // 12500
  const int agg_grid = (NN + 31) / 32;          // 3125

  // layer 0
  k_mm<CIN><<<mm_grid, 256, 0, stream>>>(x, W0, dinv, hs);
  k_agg<1><<<agg_grid, 256, 0, stream>>>(hs, rowp, col, dinv, batch, cinv, b0, hA, out);
  // layer 1
  k_mm<HIDN><<<mm_grid, 256, 0, stream>>>(hA, W1, dinv, hs);
  k_agg<1><<<agg_grid, 256, 0, stream>>>(hs, rowp, col, dinv, batch, cinv, b1, hA, out);
  // layer 2 (pool only; hout never consumed)
  k_mm<HIDN><<<mm_grid, 256, 0, stream>>>(hA, W2, dinv, hs);
  k_agg<0><<<agg_grid, 256, 0, stream>>>(hs, rowp, col, dinv, batch, cinv, b2, hA, out);
}